// Round 4
// baseline (1198.064 us; speedup 1.0000x reference)
//
#include <hip/hip_runtime.h>
#include <math.h>

// ---------------------------------------------------------------------------
// MLPEncoder (NRI encoder) on MI355X — round 4: barrier-free MFMA K-loops.
//   h1b = fusedMLP1(inputs[3200,200])            fp32 vector, 2 layers fused
//   x2  = fusedMFMA2([h1b[send]|h1b[recv]])      A per-lane global, B global,
//   h3b = fusedMLP3(incoming/9900)                 no barriers in K-loop,
//   x4  = fusedMFMA4([h3b[send]|h3b[recv]|x2])     swapped-operand MFMA
//   out = fold(BN,fc) @ x4
// ---------------------------------------------------------------------------

typedef unsigned short ushort_t;
typedef __bf16 bf16x8 __attribute__((ext_vector_type(8)));
typedef float  f32x4  __attribute__((ext_vector_type(4)));

#define E_EDGES 9900
#define NNODE   100
#define HID     256
#define M_BIG   316800
#define M_SMALL 3200

__device__ __forceinline__ float bf2f(ushort_t u) {
    union { unsigned int i; float f; } v; v.i = ((unsigned int)u) << 16; return v.f;
}
__device__ __forceinline__ ushort_t f2bf(float f) {
    union { float f; unsigned int i; } v; v.f = f;
    return (ushort_t)((v.i + 0x7fffu + ((v.i >> 16) & 1u)) >> 16);   // RNE
}
__device__ __forceinline__ float elu_f(float x) {
    return x > 0.f ? x : (expf(x) - 1.f);
}

// ---- merged weight convert+transpose: 4 matrices, 64x64 tiles -------------
// W[k][256] fp32 -> WT[col][K] bf16.  Tiles: W0 32, W1 16, W2 48, W3 16 = 112.
__global__ __launch_bounds__(256)
void wcvt4_kernel(const float* __restrict__ W0, const float* __restrict__ W1,
                  const float* __restrict__ W2, const float* __restrict__ W3,
                  ushort_t* __restrict__ T0, ushort_t* __restrict__ T1,
                  ushort_t* __restrict__ T2, ushort_t* __restrict__ T3)
{
    int bid = blockIdx.x;
    const float* W; ushort_t* WT; int K, tile;
    if (bid < 32)      { W = W0; WT = T0; K = 512; tile = bid; }
    else if (bid < 48) { W = W1; WT = T1; K = 256; tile = bid - 32; }
    else if (bid < 96) { W = W2; WT = T2; K = 768; tile = bid - 48; }
    else               { W = W3; WT = T3; K = 256; tile = bid - 96; }
    int k0 = (tile >> 2) * 64, c0 = (tile & 3) * 64;
    __shared__ float S[64][65];
    int t = threadIdx.x;
    #pragma unroll
    for (int i = 0; i < 16; ++i) {
        int idx = t + i * 256;
        S[idx >> 6][idx & 63] = W[(size_t)(k0 + (idx >> 6)) * 256 + c0 + (idx & 63)];
    }
    __syncthreads();
    int col = t & 63;
    int kb  = (t >> 6) * 16;
    ushort_t* dst = WT + (size_t)(c0 + col) * K + k0 + kb;
    #pragma unroll
    for (int jj = 0; jj < 4; ++jj) {
        ushort4 u;
        u.x = f2bf(S[kb + 4 * jj + 0][col]);
        u.y = f2bf(S[kb + 4 * jj + 1][col]);
        u.z = f2bf(S[kb + 4 * jj + 2][col]);
        u.w = f2bf(S[kb + 4 * jj + 3][col]);
        *(ushort4*)(dst + 4 * jj) = u;
    }
}

// ---- fused small 2-layer fp32 MLP: X[3200,K0] -> ELU MLP -> bf16 [3200,256]
#define FMA_ROW(ri, xs) \
    acc[ri][0] = fmaf(xs, w.x, acc[ri][0]); \
    acc[ri][1] = fmaf(xs, w.y, acc[ri][1]); \
    acc[ri][2] = fmaf(xs, w.z, acc[ri][2]); \
    acc[ri][3] = fmaf(xs, w.w, acc[ri][3]);

__global__ __launch_bounds__(256, 2)
void fused_small(const float* __restrict__ X, int K0, float xscale,
                 const float* __restrict__ W1, const float* __restrict__ b1,
                 const float* __restrict__ W2, const float* __restrict__ b2,
                 ushort_t* __restrict__ Yb)
{
    __shared__ float Xs[32][68];
    __shared__ float Ws[32][256];
    __shared__ ushort_t Hs[64][264];
    const int tid = threadIdx.x;
    const int Rbase = blockIdx.x * 64;
    const int c0 = (tid & 63) * 4;
    const int r0 = (tid >> 6) * 16;
    const int r_st = tid & 63;
    const int kb = (tid >> 6) * 8;

    float acc[16][4];
    #pragma unroll
    for (int i = 0; i < 16; ++i)
        #pragma unroll
        for (int j = 0; j < 4; ++j) acc[i][j] = 0.f;

    // layer 1
    const int nch = (K0 + 31) >> 5;
    for (int kc = 0; kc < nch; ++kc) {
        if (kc) __syncthreads();
        {
            int kg = kc * 32 + kb;
            const float* p = X + (size_t)(Rbase + r_st) * K0 + kg;
            float v[8];
            if (kg + 8 <= K0) {
                float4 a = *(const float4*)p;
                float4 b = *(const float4*)(p + 4);
                v[0]=a.x; v[1]=a.y; v[2]=a.z; v[3]=a.w;
                v[4]=b.x; v[5]=b.y; v[6]=b.z; v[7]=b.w;
            } else {
                #pragma unroll
                for (int j = 0; j < 8; ++j) v[j] = (kg + j < K0) ? p[j] : 0.f;
            }
            #pragma unroll
            for (int j = 0; j < 8; ++j) Xs[kb + j][r_st] = v[j];
        }
        #pragma unroll
        for (int m = 0; m < 8; ++m) {
            int f  = tid + m * 256;
            int kk = f >> 6;
            int cc = (f & 63) * 4;
            int kg = kc * 32 + kk;
            float4 w = (kg < K0) ? *(const float4*)&W1[(size_t)kg * 256 + cc]
                                 : make_float4(0.f, 0.f, 0.f, 0.f);
            *(float4*)&Ws[kk][cc] = w;
        }
        __syncthreads();
        #pragma unroll 8
        for (int kk = 0; kk < 32; ++kk) {
            float4 w = *(const float4*)&Ws[kk][c0];
            #pragma unroll
            for (int i = 0; i < 4; ++i) {
                float4 x = *(const float4*)&Xs[kk][r0 + 4 * i];
                FMA_ROW(4 * i + 0, x.x)
                FMA_ROW(4 * i + 1, x.y)
                FMA_ROW(4 * i + 2, x.z)
                FMA_ROW(4 * i + 3, x.w)
            }
        }
    }
    {
        float4 bv = *(const float4*)&b1[c0];
        #pragma unroll
        for (int i = 0; i < 16; ++i) {
            ushort4 u;
            u.x = f2bf(elu_f(acc[i][0] * xscale + bv.x));
            u.y = f2bf(elu_f(acc[i][1] * xscale + bv.y));
            u.z = f2bf(elu_f(acc[i][2] * xscale + bv.z));
            u.w = f2bf(elu_f(acc[i][3] * xscale + bv.w));
            *(ushort4*)&Hs[r0 + i][c0] = u;
        }
    }
    // layer 2 (K=256)
    #pragma unroll
    for (int i = 0; i < 16; ++i)
        #pragma unroll
        for (int j = 0; j < 4; ++j) acc[i][j] = 0.f;
    for (int kc = 0; kc < 8; ++kc) {
        __syncthreads();
        {
            union { uint4 qv; ushort_t s[8]; } u;
            u.qv = *(const uint4*)&Hs[r_st][kc * 32 + kb];
            #pragma unroll
            for (int j = 0; j < 8; ++j) Xs[kb + j][r_st] = bf2f(u.s[j]);
        }
        #pragma unroll
        for (int m = 0; m < 8; ++m) {
            int f  = tid + m * 256;
            int kk = f >> 6;
            int cc = (f & 63) * 4;
            *(float4*)&Ws[kk][cc] = *(const float4*)&W2[(size_t)(kc * 32 + kk) * 256 + cc];
        }
        __syncthreads();
        #pragma unroll 8
        for (int kk = 0; kk < 32; ++kk) {
            float4 w = *(const float4*)&Ws[kk][c0];
            #pragma unroll
            for (int i = 0; i < 4; ++i) {
                float4 x = *(const float4*)&Xs[kk][r0 + 4 * i];
                FMA_ROW(4 * i + 0, x.x)
                FMA_ROW(4 * i + 1, x.y)
                FMA_ROW(4 * i + 2, x.z)
                FMA_ROW(4 * i + 3, x.w)
            }
        }
    }
    {
        float4 bv = *(const float4*)&b2[c0];
        #pragma unroll
        for (int i = 0; i < 16; ++i) {
            int R = Rbase + r0 + i;
            ushort4 u;
            u.x = f2bf(elu_f(acc[i][0] + bv.x));
            u.y = f2bf(elu_f(acc[i][1] + bv.y));
            u.z = f2bf(elu_f(acc[i][2] + bv.z));
            u.w = f2bf(elu_f(acc[i][3] + bv.w));
            *(ushort4*)&Yb[(size_t)R * 256 + c0] = u;
        }
    }
}

// ---- fused 2-layer MFMA MLP, barrier-free K-loops -------------------------
// MODE 2: L1 in = [h1b[send]|h1b[recv]] (K1=512); epilogue: e2n partials->aux
// MODE 3: L1 in = [h3b[send]|h3b[recv]|x2[R]] (K1=768); in-place; stats->aux
// Swapped-operand MFMA: mfma(Wfrag, edgefrag) -> lane holds edge=ln15,
// channels 4q+reg (consecutive) => b64 LDS park writes.
template<int MODE>
__global__ __launch_bounds__(256, 3)
void fused_mfma(const ushort_t* __restrict__ Gb,
                const ushort_t* __restrict__ X2,
                const ushort_t* __restrict__ W1T,   // [256][K1] bf16
                const float* __restrict__ bias1,
                const ushort_t* __restrict__ W2T,   // [256][256] bf16
                const float* __restrict__ bias2,
                ushort_t* __restrict__ Y,
                float* __restrict__ aux)
{
    constexpr int K1  = (MODE == 2) ? 512 : 768;
    constexpr int NST = K1 / 32;
    __shared__ ushort_t Hb[64][264];

    const int tid = threadIdx.x;
    const int w = tid >> 6;
    const int l = tid & 63;
    const int ln15 = l & 15;
    const int q = l >> 4;
    const int klane = 8 * q;
    const int Rbase = blockIdx.x * 64;

    // per-lane gather offsets (elements) for the 4 row-tiles this lane feeds
    int oS[4], oR[4], oX[4];
    #pragma unroll
    for (int r = 0; r < 4; ++r) {
        int R = Rbase + 16 * r + ln15;
        int b = R / E_EDGES;
        int e = R - b * E_EDGES;
        int i = e / 99;
        int kk = e - i * 99;
        int j = kk + (kk >= i ? 1 : 0);
        oS[r] = (b * NNODE + j) * HID;
        oR[r] = (b * NNODE + i) * HID;
        oX[r] = R * 256;
    }
    int wch[4];   // B-channel row offsets into WT (elements)
    #pragma unroll
    for (int c = 0; c < 4; ++c) wch[c] = (w * 64 + 16 * c + ln15) * K1;

    f32x4 acc[4][4];
    #pragma unroll
    for (int r = 0; r < 4; ++r)
        #pragma unroll
        for (int c = 0; c < 4; ++c)
            acc[r][c][0] = acc[r][c][1] = acc[r][c][2] = acc[r][c][3] = 0.f;

    // ---------------- layer 1: no barriers, 1-deep prefetch ----------------
    auto loadA1 = [&](int kc, bf16x8 a[4]) {
        #pragma unroll
        for (int r = 0; r < 4; ++r) {
            if (MODE == 3 && kc >= 16)
                a[r] = *(const bf16x8*)(X2 + oX[r] + (kc - 16) * 32 + klane);
            else if (kc < 8)
                a[r] = *(const bf16x8*)(Gb + oS[r] + kc * 32 + klane);
            else
                a[r] = *(const bf16x8*)(Gb + oR[r] + (kc - 8) * 32 + klane);
        }
    };
    auto loadB1 = [&](int kc, bf16x8 b[4]) {
        #pragma unroll
        for (int c = 0; c < 4; ++c)
            b[c] = *(const bf16x8*)(W1T + wch[c] + kc * 32 + klane);
    };

    {
        bf16x8 a0[4], b0[4];
        loadA1(0, a0);
        loadB1(0, b0);
        #pragma unroll
        for (int kc = 0; kc < NST; ++kc) {
            bf16x8 a1[4], b1[4];
            if (kc + 1 < NST) { loadA1(kc + 1, a1); loadB1(kc + 1, b1); }
            #pragma unroll
            for (int r = 0; r < 4; ++r)
                #pragma unroll
                for (int c = 0; c < 4; ++c)
                    acc[r][c] = __builtin_amdgcn_mfma_f32_16x16x32_bf16(b0[c], a0[r], acc[r][c], 0, 0, 0);
            #pragma unroll
            for (int r = 0; r < 4; ++r) { a0[r] = a1[r]; b0[r] = b1[r]; }
        }
    }

    // hidden = ELU(acc + b1) -> Hb  (lane: edge=16r+ln15, chan=w*64+16c+4q+reg)
    #pragma unroll
    for (int c = 0; c < 4; ++c) {
        float4 bv = *(const float4*)&bias1[w * 64 + 16 * c + 4 * q];
        #pragma unroll
        for (int r = 0; r < 4; ++r) {
            ushort4 u;
            u.x = f2bf(elu_f(acc[r][c][0] + bv.x));
            u.y = f2bf(elu_f(acc[r][c][1] + bv.y));
            u.z = f2bf(elu_f(acc[r][c][2] + bv.z));
            u.w = f2bf(elu_f(acc[r][c][3] + bv.w));
            *(ushort4*)&Hb[16 * r + ln15][w * 64 + 16 * c + 4 * q] = u;
        }
    }
    __syncthreads();

    // ---------------- layer 2: K=256, A from Hb, B prefetched --------------
    #pragma unroll
    for (int r = 0; r < 4; ++r)
        #pragma unroll
        for (int c = 0; c < 4; ++c)
            acc[r][c][0] = acc[r][c][1] = acc[r][c][2] = acc[r][c][3] = 0.f;

    int wch2[4];
    #pragma unroll
    for (int c = 0; c < 4; ++c) wch2[c] = (w * 64 + 16 * c + ln15) * 256;
    auto loadB2 = [&](int kc, bf16x8 b[4]) {
        #pragma unroll
        for (int c = 0; c < 4; ++c)
            b[c] = *(const bf16x8*)(W2T + wch2[c] + kc * 32 + klane);
    };
    {
        bf16x8 b0[4];
        loadB2(0, b0);
        #pragma unroll
        for (int kc = 0; kc < 8; ++kc) {
            bf16x8 af[4];
            #pragma unroll
            for (int r = 0; r < 4; ++r)
                af[r] = *(const bf16x8*)&Hb[16 * r + ln15][kc * 32 + klane];
            bf16x8 b1[4];
            if (kc < 7) loadB2(kc + 1, b1);
            #pragma unroll
            for (int r = 0; r < 4; ++r)
                #pragma unroll
                for (int c = 0; c < 4; ++c)
                    acc[r][c] = __builtin_amdgcn_mfma_f32_16x16x32_bf16(b0[c], af[r], acc[r][c], 0, 0, 0);
            #pragma unroll
            for (int c = 0; c < 4; ++c) b0[c] = b1[c];
        }
    }
    __syncthreads();    // Hb reads done before overwrite

    // out = ELU(acc + b2) -> Hb park, then coalesced global write
    #pragma unroll
    for (int c = 0; c < 4; ++c) {
        float4 bv = *(const float4*)&bias2[w * 64 + 16 * c + 4 * q];
        #pragma unroll
        for (int r = 0; r < 4; ++r) {
            ushort4 u;
            u.x = f2bf(elu_f(acc[r][c][0] + bv.x));
            u.y = f2bf(elu_f(acc[r][c][1] + bv.y));
            u.z = f2bf(elu_f(acc[r][c][2] + bv.z));
            u.w = f2bf(elu_f(acc[r][c][3] + bv.w));
            *(ushort4*)&Hb[16 * r + ln15][w * 64 + 16 * c + 4 * q] = u;
        }
    }
    __syncthreads();

    #pragma unroll
    for (int m = 0; m < 8; ++m) {
        int ch = tid + m * 256;
        int row = ch >> 5;
        int o = (ch & 31) * 8;
        *(uint4*)&Y[((size_t)(Rbase + row)) * 256 + o] = *(const uint4*)&Hb[row][o];
    }

    // fused epilogue reductions over this block's 64 output rows
    {
        int c = tid;   // channel 0..255
        if (MODE == 2) {
            int bn = Rbase / 99;
            int left = 99 - (Rbase - bn * 99);
            float s = 0.f;
            for (int r = 0; r < 64; ++r) {
                s += bf2f(Hb[r][c]);
                if (--left == 0) { atomicAdd(&aux[(size_t)bn * 256 + c], s); s = 0.f; ++bn; left = 99; }
            }
            atomicAdd(&aux[(size_t)bn * 256 + c], s);
        } else {
            float s = 0.f, q2 = 0.f;
            for (int r = 0; r < 64; ++r) {
                float v = bf2f(Hb[r][c]);
                s += v;
                q2 = fmaf(v, v, q2);
            }
            atomicAdd(&aux[c], s);
            atomicAdd(&aux[256 + c], q2);
        }
    }
}

// ---- fold BN + fc into Wfold[256][2], bfold[2] ----------------------------
__global__ __launch_bounds__(256)
void fold_kernel(const float* __restrict__ stats,
                 const float* __restrict__ gamma, const float* __restrict__ beta,
                 const float* __restrict__ fcW, const float* __restrict__ fcb,
                 float* __restrict__ fold)
{
    __shared__ float red0[256], red1[256];
    int c = threadIdx.x;
    float mean  = stats[c] * (1.f / M_BIG);
    float var   = stats[256 + c] * (1.f / M_BIG) - mean * mean;
    float inv   = rsqrtf(var + 1e-5f);
    float scale = inv * gamma[c];
    float sh    = beta[c] - mean * scale;
    float w0 = fcW[c * 2 + 0], w1 = fcW[c * 2 + 1];
    fold[c * 2 + 0] = scale * w0;
    fold[c * 2 + 1] = scale * w1;
    red0[c] = sh * w0;
    red1[c] = sh * w1;
    __syncthreads();
    for (int off = 128; off > 0; off >>= 1) {
        if (c < off) { red0[c] += red0[c + off]; red1[c] += red1[c + off]; }
        __syncthreads();
    }
    if (c == 0) {
        fold[512] = red0[0] + fcb[0];
        fold[513] = red1[0] + fcb[1];
    }
}

// ---- final: out[R][2] = x4_row . Wfold + bfold  (wave per row) ------------
__global__ __launch_bounds__(256)
void final_kernel(const ushort_t* __restrict__ x4, const float* __restrict__ fold,
                  float* __restrict__ out)
{
    int tid  = threadIdx.x;
    int lane = tid & 63;
    int wave = tid >> 6;
    int R = blockIdx.x * 4 + wave;
    int c0 = lane * 4;
    union { uint2 qv; ushort_t s[4]; } u;
    u.qv = *(const uint2*)(x4 + (size_t)R * 256 + c0);
    float a0 = 0.f, a1 = 0.f;
    #pragma unroll
    for (int j = 0; j < 4; ++j) {
        float v = bf2f(u.s[j]);
        a0 = fmaf(v, fold[(c0 + j) * 2 + 0], a0);
        a1 = fmaf(v, fold[(c0 + j) * 2 + 1], a1);
    }
    #pragma unroll
    for (int off = 32; off > 0; off >>= 1) {
        a0 += __shfl_down(a0, off);
        a1 += __shfl_down(a1, off);
    }
    if (lane == 0) {
        out[(size_t)R * 2 + 0] = a0 + fold[512];
        out[(size_t)R * 2 + 1] = a1 + fold[513];
    }
}

extern "C" void kernel_launch(void* const* d_in, const int* in_sizes, int n_in,
                              void* d_out, int out_size, void* d_ws, size_t ws_size,
                              hipStream_t stream)
{
    (void)in_sizes; (void)n_in; (void)out_size; (void)ws_size;

    const float* inputs = (const float*)d_in[0];
    const float* m1W1 = (const float*)d_in[3];
    const float* m1b1 = (const float*)d_in[4];
    const float* m1W2 = (const float*)d_in[5];
    const float* m1b2 = (const float*)d_in[6];
    const float* m2W1 = (const float*)d_in[7];
    const float* m2b1 = (const float*)d_in[8];
    const float* m2W2 = (const float*)d_in[9];
    const float* m2b2 = (const float*)d_in[10];
    const float* m3W1 = (const float*)d_in[11];
    const float* m3b1 = (const float*)d_in[12];
    const float* m3W2 = (const float*)d_in[13];
    const float* m3b2 = (const float*)d_in[14];
    const float* m4W1 = (const float*)d_in[15];
    const float* m4b1 = (const float*)d_in[16];
    const float* m4W2 = (const float*)d_in[17];
    const float* m4b2 = (const float*)d_in[18];
    const float* gamma = (const float*)d_in[19];
    const float* beta  = (const float*)d_in[20];
    const float* fcW   = (const float*)d_in[21];
    const float* fcb   = (const float*)d_in[22];
    float* out = (float*)d_out;

    // ---- workspace layout (~168 MB) ----
    char* ws = (char*)d_ws;
    const size_t BIGB  = (size_t)M_BIG * 256 * 2;       // 162,201,600
    const size_t HB    = (size_t)M_SMALL * 256 * 2;     // 1,638,400
    const size_t SMALL = (size_t)M_SMALL * 256 * 4;     // 3,276,800
    ushort_t* bigX     = (ushort_t*)ws;                       // x2 then x4
    ushort_t* hbuf     = (ushort_t*)(ws + BIGB);              // h1b then h3b
    float*    incoming = (float*)(ws + BIGB + HB);
    float*    stats    = (float*)(ws + BIGB + HB + SMALL);    // 512 f32
    float*    fold     = stats + 512;                         // 514 f32
    ushort_t* w1t      = (ushort_t*)(ws + BIGB + HB + SMALL + 8192);
    ushort_t* w2t      = w1t + 512 * 256;
    ushort_t* w4at     = w2t + 256 * 256;
    ushort_t* w4bt     = w4at + 768 * 256;

    hipMemsetAsync(stats, 0, 2048, stream);
    hipMemsetAsync(incoming, 0, SMALL, stream);

    dim3 blk(256);
    wcvt4_kernel<<<112, blk, 0, stream>>>(m2W1, m2W2, m4W1, m4W2, w1t, w2t, w4at, w4bt);
    // MLP1 (2 layers fused): inputs[3200,200] -> hbuf (bf16 h1)
    fused_small<<<M_SMALL / 64, blk, 0, stream>>>(inputs, 200, 1.f, m1W1, m1b1, m1W2, m1b2, hbuf);
    // fused MLP2 (MFMA): gather h1b -> x2 (bigX); epilogue: e2n -> incoming
    fused_mfma<2><<<M_BIG / 64, blk, 0, stream>>>(hbuf, bigX, w1t, m2b1, w2t, m2b2, bigX, incoming);
    // MLP3 (2 layers fused): incoming/9900 -> hbuf (bf16 h3)
    fused_small<<<M_SMALL / 64, blk, 0, stream>>>(incoming, 256, 1.f / 9900.f, m3W1, m3b1, m3W2, m3b2, hbuf);
    // fused MLP4 (MFMA): gather h3b + skip x2 -> x4 in-place; epilogue: stats
    fused_mfma<3><<<M_BIG / 64, blk, 0, stream>>>(hbuf, bigX, w4at, m4b1, w4bt, m4b2, bigX, stats);
    // BN fold -> final linear
    fold_kernel<<<1, blk, 0, stream>>>(stats, gamma, beta, fcW, fcb, fold);
    final_kernel<<<M_BIG / 4, blk, 0, stream>>>(bigX, fold, out);
}